// Round 7
// baseline (249.874 us; speedup 1.0000x reference)
//
#include <hip/hip_runtime.h>
#include <hip/hip_bf16.h>
#include <stdint.h>

typedef __attribute__((ext_vector_type(8))) short bf16x8;
typedef __attribute__((ext_vector_type(4))) float f32x4;
typedef __attribute__((ext_vector_type(4))) unsigned short u16x4;

#define B_ 4
#define T_ 2048
#define C_ 1024
#define H_ 16
#define D_ 64

// round-to-nearest-even fp32 -> bf16
__device__ __forceinline__ unsigned short f2bf(float f) {
  union { float f; uint32_t u; } v; v.f = f;
  uint32_t u = v.u;
  uint32_t r = (u + 0x7FFFu + ((u >> 16) & 1u)) >> 16;
  return (unsigned short)r;
}

// fused cast of all three fp32 inputs -> bf16 (one launch instead of three)
__global__ void __launch_bounds__(256) cast_all(const float* __restrict__ x,
                                                const float* __restrict__ wqkv,
                                                const float* __restrict__ wout,
                                                unsigned short* __restrict__ xb,
                                                unsigned short* __restrict__ wqkvb,
                                                unsigned short* __restrict__ woutb) {
  int bid = blockIdx.x;
  const float* src; unsigned short* dst; int i;
  if (bid < 8192)       { src = x;    dst = xb;    i = bid * 256 + threadIdx.x; }
  else if (bid < 11264) { src = wqkv; dst = wqkvb; i = (bid - 8192) * 256 + threadIdx.x; }
  else                  { src = wout; dst = woutb; i = (bid - 11264) * 256 + threadIdx.x; }
  float4 f = ((const float4*)src)[i];
  u16x4 o;
  o[0] = f2bf(f.x); o[1] = f2bf(f.y); o[2] = f2bf(f.z); o[3] = f2bf(f.w);
  ((u16x4*)dst)[i] = o;
}

// ---------------------------------------------------------------------------
// QKV GEMM: C[8192,3072] = A[8192,1024] * W[3072,1024]^T, bf16, fp32 acc.
// 256x128 block tile, BK=32, 4 waves, per-wave 128x64 (acc[8][4]).
// 2-phase dbuf staging via global_load_lds width=16 (proven structure).
// Launched as TWO M-half dispatches (bm0 = 0 / 4096) so the profile's top-5
// exposes attn/gemm_out durations instead of five copies of this kernel.
// Epilogue: Q/K blocks -> LDS [128][132] transpose -> coalesced 16B scatter;
// V blocks -> packed u16x4 stores to vt[B,H,D,T] (transposed for attn's PV).
// ---------------------------------------------------------------------------
__global__ void __launch_bounds__(256, 2) gemm_qkv(const unsigned short* __restrict__ A,
                                                   const unsigned short* __restrict__ Bm,
                                                   unsigned short* __restrict__ qb,
                                                   unsigned short* __restrict__ kb,
                                                   unsigned short* __restrict__ vb,
                                                   int bm0) {
  __shared__ short lds[24576];  // 48KB: 2 bufs x (A 256x32 + B 128x32 shorts)
  const int tid = threadIdx.x;
  const int bm = bm0 + blockIdx.y * 256;
  const int bn = blockIdx.x * 128;

  const int wave = tid >> 6;
  const int l = tid & 63;
  const int wm = wave >> 1, wn = wave & 1;   // wave-row (128 m), wave-col (64 n)
  const int lm = l & 15, lq = l >> 4;
  const int lr = l >> 2;           // row within 16-row staging chunk
  const int lc = (l & 3) << 3;     // k-col {0,8,16,24}

  f32x4 acc[8][4];
#pragma unroll
  for (int i = 0; i < 8; i++)
#pragma unroll
    for (int j = 0; j < 4; j++) acc[i][j] = (f32x4){0.f, 0.f, 0.f, 0.f};

  // staging: 24 chunks of 16 rows x 32 shorts (1KB); 0..15 -> A, 16..23 -> B.
  const unsigned short* gs[6];
  int ldo[6];
#pragma unroll
  for (int i = 0; i < 6; i++) {
    int c = wave * 6 + i;            // 0..23, wave-uniform
    if (c < 16) {
      gs[i] = A + (size_t)(bm + 16 * c + lr) * 1024 + lc;
      ldo[i] = c * 512;                      // A region [0,8192)
    } else {
      gs[i] = Bm + (size_t)(bn + 16 * (c - 16) + lr) * 1024 + lc;
      ldo[i] = 8192 + (c - 16) * 512;        // B region [8192,12288)
    }
  }

#define STAGE(curb, kk)                                                          \
  do {                                                                           \
    _Pragma("unroll")                                                            \
    for (int i = 0; i < 6; i++) {                                                \
      __builtin_amdgcn_global_load_lds(                                          \
          (__attribute__((address_space(1))) void*)(uintptr_t)(const void*)(gs[i] + (kk)), \
          (__attribute__((address_space(3))) void*)(lds + ldo[i] + (curb) * 12288),        \
          16, 0, 0);                                                             \
    }                                                                            \
  } while (0)

  STAGE(0, 0);
  int cur = 0;
  __syncthreads();  // prologue tile landed (vmcnt(0) drain) + visible to all

  for (int k0 = 0; k0 < 1024; k0 += 32) {
    if (k0 + 32 < 1024) STAGE(cur ^ 1, k0 + 32);  // issue next tile EARLY
    const short* As_ = lds + cur * 12288;
    const short* Bs_ = lds + cur * 12288 + 8192;
    bf16x8 Bf[4];
#pragma unroll
    for (int j = 0; j < 4; j++)
      Bf[j] = *(const bf16x8*)&Bs_[(wn * 64 + 16 * j + lm) * 32 + 8 * lq];
#pragma unroll
    for (int h = 0; h < 2; h++) {   // two m-halves reuse Bf
      bf16x8 Af[4];
#pragma unroll
      for (int i = 0; i < 4; i++)
        Af[i] = *(const bf16x8*)&As_[(wm * 128 + 64 * h + 16 * i + lm) * 32 + 8 * lq];
#pragma unroll
      for (int i = 0; i < 4; i++)
#pragma unroll
        for (int j = 0; j < 4; j++)
          acc[4 * h + i][j] =
              __builtin_amdgcn_mfma_f32_16x16x32_bf16(Af[i], Bf[j], acc[4 * h + i][j], 0, 0, 0);
    }
    __syncthreads();  // next tile's loads drained + everyone done reading cur
    cur ^= 1;
  }
#undef STAGE

  // C/D layout: col = lane&15, row = (lane>>4)*4 + reg  [measured m89/m91]
  if (bn >= 2048) {
    // V block: store TRANSPOSED vt[b,h,d,t]; acc[.][.][0..3] = 4 consecutive t.
#pragma unroll
    for (int h = 0; h < 2; h++)
#pragma unroll
      for (int i = 0; i < 4; i++)
#pragma unroll
        for (int j = 0; j < 4; j++) {
          int m0 = bm + wm * 128 + 64 * h + 16 * i + 4 * lq;   // t base (4-aligned)
          int n = (bn - 2048) + wn * 64 + 16 * j + lm;         // 0..1023
          int hh = n >> 6, d = n & 63;
          int b = m0 >> 11, t = m0 & 2047;
          u16x4 o;
#pragma unroll
          for (int r = 0; r < 4; r++) o[r] = f2bf(acc[4 * h + i][j][r]);
          *(u16x4*)&vb[(((size_t)(b * 16 + hh)) * 64 + d) * 2048 + t] = o;
        }
  } else {
    // Q/K block: LDS transpose [128][132] in two half-passes -> coalesced 16B stores
#pragma unroll
    for (int p = 0; p < 2; ++p) {
      if (p) __syncthreads();  // pass-0 reads done before overwrite
      if (wm == p) {
#pragma unroll
        for (int h = 0; h < 2; h++)
#pragma unroll
          for (int i = 0; i < 4; i++)
#pragma unroll
            for (int j = 0; j < 4; j++)
#pragma unroll
              for (int r = 0; r < 4; r++)
                lds[(64 * h + 16 * i + 4 * lq + r) * 132 + wn * 64 + 16 * j + lm] =
                    (short)f2bf(acc[4 * h + i][j][r]);
      }
      __syncthreads();
#pragma unroll
      for (int k = 0; k < 8; k++) {
        int c = tid + 256 * k;       // 2048 chunks of 8 shorts
        int row = c >> 4;            // 0..127
        int col = (c & 15) << 3;     // 0..120
        bf16x8 v = *(const bf16x8*)&lds[row * 132 + col];
        int m = bm + 128 * p + row, n = bn + col;
        int which = n >> 10, rem = n & 1023;
        int hh = rem >> 6, d = rem & 63;     // d 8-aligned, within one head
        int b = m >> 11, t = m & 2047;
        unsigned short* dst = (which == 0) ? qb : kb;
        *(bf16x8*)&dst[(((size_t)(b * 16 + hh)) * 2048 + t) * 64 + d] = v;
      }
    }
  }
}

// ---------------------------------------------------------------------------
// Out-proj GEMM: C[8192,1024] = A[8192,1024] * W[1024,1024]^T, fp32 out.
// 128x128 tile, BK=32, 2-phase dbuf (proven round-3 structure).
// ---------------------------------------------------------------------------
__global__ void __launch_bounds__(256) gemm_out(const unsigned short* __restrict__ A,
                                                const unsigned short* __restrict__ Bm,
                                                float* __restrict__ fo) {
  __shared__ short lds[16384];
  const int tid = threadIdx.x;
  const int bm = blockIdx.y * 128;
  const int bn = blockIdx.x * 128;
  const int wave = tid >> 6;
  const int l = tid & 63;
  const int wm = wave >> 1, wn = wave & 1;
  const int lm = l & 15, lq = l >> 4;
  const int lr = l >> 2;
  const int lc = (l & 3) << 3;

  f32x4 acc[4][4];
#pragma unroll
  for (int i = 0; i < 4; i++)
#pragma unroll
    for (int j = 0; j < 4; j++) acc[i][j] = (f32x4){0.f, 0.f, 0.f, 0.f};

  const unsigned short* gsrc[4];
  int ldoff[4];
#pragma unroll
  for (int i = 0; i < 4; i++) {
    int c = wave * 4 + i;
    if (c < 8) {
      gsrc[i] = A + (size_t)(bm + 16 * c + lr) * 1024 + lc;
      ldoff[i] = (16 * c) * 32;
    } else {
      gsrc[i] = Bm + (size_t)(bn + 16 * (c - 8) + lr) * 1024 + lc;
      ldoff[i] = 8192 + (16 * (c - 8)) * 32;
    }
  }

#define STAGE(curb, kk)                                                          \
  do {                                                                           \
    _Pragma("unroll")                                                            \
    for (int i = 0; i < 4; i++) {                                                \
      __builtin_amdgcn_global_load_lds(                                          \
          (__attribute__((address_space(1))) void*)(uintptr_t)(const void*)(gsrc[i] + (kk)), \
          (__attribute__((address_space(3))) void*)(lds + ldoff[i] + (curb) * 4096),         \
          16, 0, 0);                                                             \
    }                                                                            \
  } while (0)

  STAGE(0, 0);
  int cur = 0;
  __syncthreads();

  for (int k0 = 0; k0 < 1024; k0 += 32) {
    if (k0 + 32 < 1024) STAGE(cur ^ 1, k0 + 32);
    bf16x8 af[4], bfr[4];
#pragma unroll
    for (int i = 0; i < 4; i++)
      af[i] = *(const bf16x8*)&lds[cur * 4096 + (wm * 64 + 16 * i + lm) * 32 + 8 * lq];
#pragma unroll
    for (int j = 0; j < 4; j++)
      bfr[j] = *(const bf16x8*)&lds[8192 + cur * 4096 + (wn * 64 + 16 * j + lm) * 32 + 8 * lq];
#pragma unroll
    for (int i = 0; i < 4; i++)
#pragma unroll
      for (int j = 0; j < 4; j++)
        acc[i][j] = __builtin_amdgcn_mfma_f32_16x16x32_bf16(af[i], bfr[j], acc[i][j], 0, 0, 0);
    __syncthreads();
    cur ^= 1;
  }
#undef STAGE

#pragma unroll
  for (int i = 0; i < 4; i++)
#pragma unroll
    for (int j = 0; j < 4; j++)
#pragma unroll
      for (int r = 0; r < 4; r++) {
        int m = bm + wm * 64 + 16 * i + 4 * lq + r;
        int n = bn + wn * 64 + 16 * j + lm;
        fo[(size_t)m * 1024 + n] = acc[i][j][r];
      }
}

// ---------------------------------------------------------------------------
// Sliding-window causal flash attention, 4 q-subtiles (64 queries) per wave.
// One wave owns q rows [t0, t0+64); K/V chunk loads (32 keys) are SHARED across
// the 4 16-row subtiles (4x less VMEM issue than 1-tile-per-wave), and the 4
// independent QK->softmax->PV chains per chunk provide ILP. Wave-uniform 'act'
// guard skips subtiles whose window misses the chunk entirely. Masked-row
// poison (exp2(-1e30 - (-1e30)) = 1) is guarded by zeroing p for masked s.
// q/k in [B,H,T,D] bf16; v transposed vt[B,H,D,T]; out [B,T,H*D] bf16.
// ---------------------------------------------------------------------------
__global__ void __launch_bounds__(256) attn_swa(const unsigned short* __restrict__ Qb,
                                               const unsigned short* __restrict__ Kb,
                                               const unsigned short* __restrict__ Vt,
                                               unsigned short* __restrict__ Ob) {
  __shared__ short P[4][64 * 40];  // per-wave P tiles (4 subtiles x 16 rows), stride 40
  const int wv = threadIdx.x >> 6;
  const int l = threadIdx.x & 63;
  const int wid = blockIdx.x * 4 + wv;   // 0..2047
  const int bh = wid >> 5;               // 32 q-groups per (b,h)
  const int t0 = (wid & 31) << 6;        // 64-query group base
  const int lm = l & 15, lq = l >> 4;
  const size_t base = (size_t)bh * (T_ * D_);

  // Q A-fragments per subtile: rows t0+16*qt+lm, two d-halves
  bf16x8 aq[4][2];
#pragma unroll
  for (int qt = 0; qt < 4; qt++) {
    aq[qt][0] = *(const bf16x8*)(Qb + base + (size_t)(t0 + 16 * qt + lm) * 64 + 8 * lq);
    aq[qt][1] = *(const bf16x8*)(Qb + base + (size_t)(t0 + 16 * qt + lm) * 64 + 32 + 8 * lq);
  }

  float mst[4][4], lst[4][4];
  f32x4 Oa[4][4];  // [qt][jt]
#pragma unroll
  for (int qt = 0; qt < 4; qt++)
#pragma unroll
    for (int r = 0; r < 4; r++) { mst[qt][r] = -1e30f; lst[qt][r] = 0.f; }
#pragma unroll
  for (int qt = 0; qt < 4; qt++)
#pragma unroll
    for (int jt = 0; jt < 4; jt++) Oa[qt][jt] = (f32x4){0.f, 0.f, 0.f, 0.f};

  const float cs = 0.125f * 1.44269504f;  // scale * log2(e)
  int jstart = t0 - 128; if (jstart < 0) jstart = 0;

  for (int j0 = jstart; j0 < t0 + 64; j0 += 32) {
    // subtile-active guards (wave-uniform): chunk [j0,j0+31] overlaps
    // window union of subtile qt: [t0q-128, t0q+15]
    bool act[4];
#pragma unroll
    for (int qt = 0; qt < 4; qt++) {
      int t0q = t0 + 16 * qt;
      act[qt] = (j0 <= t0q + 15) && (j0 + 159 >= t0q);
    }
    // K rows j0..j0+31 <= t0+63 <= 2047: no clamp needed
    f32x4 S[4][2];
#pragma unroll
    for (int hh = 0; hh < 2; hh++) {
      int kr = j0 + 16 * hh + lm;
      bf16x8 bkA = *(const bf16x8*)(Kb + base + (size_t)kr * 64 + 8 * lq);
      bf16x8 bkB = *(const bf16x8*)(Kb + base + (size_t)kr * 64 + 32 + 8 * lq);
#pragma unroll
      for (int qt = 0; qt < 4; qt++)
        if (act[qt]) {
          f32x4 s = (f32x4){0.f, 0.f, 0.f, 0.f};
          s = __builtin_amdgcn_mfma_f32_16x16x32_bf16(aq[qt][0], bkA, s, 0, 0, 0);
          s = __builtin_amdgcn_mfma_f32_16x16x32_bf16(aq[qt][1], bkB, s, 0, 0, 0);
          S[qt][hh] = s;
        }
    }
    // online softmax per subtile
#pragma unroll
    for (int qt = 0; qt < 4; qt++)
      if (act[qt]) {
        int t0q = t0 + 16 * qt;
        float p0s[4], p1s[4], al[4];
#pragma unroll
        for (int r = 0; r < 4; r++) {
          int t = t0q + 4 * lq + r;
          int ja = j0 + lm, jb = j0 + 16 + lm;
          float s0 = ((ja <= t) && (ja + 128 >= t)) ? S[qt][0][r] * cs : -1e30f;
          float s1 = ((jb <= t) && (jb + 128 >= t)) ? S[qt][1][r] * cs : -1e30f;
          float m2 = fmaxf(s0, s1);
#pragma unroll
          for (int off = 1; off < 16; off <<= 1) m2 = fmaxf(m2, __shfl_xor(m2, off));
          float mn = fmaxf(mst[qt][r], m2);
          float a = __builtin_amdgcn_exp2f(mst[qt][r] - mn);
          float p0 = (s0 > -1e29f) ? __builtin_amdgcn_exp2f(s0 - mn) : 0.f;
          float p1 = (s1 > -1e29f) ? __builtin_amdgcn_exp2f(s1 - mn) : 0.f;
          float ps = p0 + p1;
#pragma unroll
          for (int off = 1; off < 16; off <<= 1) ps += __shfl_xor(ps, off);
          lst[qt][r] = lst[qt][r] * a + ps;
          mst[qt][r] = mn;
          al[r] = a; p0s[r] = p0; p1s[r] = p1;
        }
#pragma unroll
        for (int jt = 0; jt < 4; jt++)
#pragma unroll
          for (int r = 0; r < 4; r++) Oa[qt][jt][r] *= al[r];
        // P: C-layout -> LDS -> A-layout; same-wave LDS, no barrier needed
#pragma unroll
        for (int r = 0; r < 4; r++) {
          P[wv][(qt * 16 + 4 * lq + r) * 40 + lm] = (short)f2bf(p0s[r]);
          P[wv][(qt * 16 + 4 * lq + r) * 40 + 16 + lm] = (short)f2bf(p1s[r]);
        }
      }
    // V fragments shared across subtiles: vt[d=16jt+lm][j0+8lq .. +7]
    bf16x8 vf[4];
#pragma unroll
    for (int jt = 0; jt < 4; jt++)
      vf[jt] = *(const bf16x8*)(Vt + base + (size_t)(16 * jt + lm) * 2048 + j0 + 8 * lq);
#pragma unroll
    for (int qt = 0; qt < 4; qt++)
      if (act[qt]) {
        bf16x8 pa = *(const bf16x8*)&P[wv][(qt * 16 + lm) * 40 + 8 * lq];
#pragma unroll
        for (int jt = 0; jt < 4; jt++)
          Oa[qt][jt] = __builtin_amdgcn_mfma_f32_16x16x32_bf16(pa, vf[jt], Oa[qt][jt], 0, 0, 0);
      }
  }
  const int b = bh >> 4, h = bh & 15;
#pragma unroll
  for (int qt = 0; qt < 4; qt++)
#pragma unroll
    for (int r = 0; r < 4; r++) {
      float inv = 1.0f / lst[qt][r];
      int t = t0 + 16 * qt + 4 * lq + r;
#pragma unroll
      for (int jt = 0; jt < 4; jt++) {
        int c = h * 64 + 16 * jt + lm;
        Ob[((size_t)(b * T_ + t)) * 1024 + c] = f2bf(Oa[qt][jt][r] * inv);
      }
    }
}

extern "C" void kernel_launch(void* const* d_in, const int* in_sizes, int n_in,
                              void* d_out, int out_size, void* d_ws, size_t ws_size,
                              hipStream_t stream) {
  const float* x = (const float*)d_in[0];       // [4,2048,1024]
  const float* w_qkv = (const float*)d_in[1];   // [3072,1024]
  const float* w_out = (const float*)d_in[2];   // [1024,1024]
  float* out = (float*)d_out;                   // [4,2048,1024] fp32

  // workspace layout (bf16 = unsigned short), ~72 MB total
  unsigned short* xb = (unsigned short*)d_ws;                // 8192*1024 (reused as attn out)
  unsigned short* wqkvb = xb + (size_t)8192 * 1024;          // 3072*1024
  unsigned short* woutb = wqkvb + (size_t)3072 * 1024;       // 1024*1024
  unsigned short* qb = woutb + (size_t)1024 * 1024;          // 64*2048*64
  unsigned short* kb = qb + (size_t)64 * 2048 * 64;
  unsigned short* vb = kb + (size_t)64 * 2048 * 64;          // holds vt[B,H,D,T]

  cast_all<<<12288, 256, 0, stream>>>(x, w_qkv, w_out, xb, wqkvb, woutb);

  // qkv = x @ w_qkv^T (two M-half dispatches for profile visibility)
  gemm_qkv<<<dim3(24, 16), 256, 0, stream>>>(xb, wqkvb, qb, kb, vb, 0);
  gemm_qkv<<<dim3(24, 16), 256, 0, stream>>>(xb, wqkvb, qb, kb, vb, 4096);

  // sliding-window attention -> [B,T,C] bf16 (aliases xb; dead after gemm_qkv)
  attn_swa<<<512, 256, 0, stream>>>(qb, kb, vb, xb);

  // out = attn @ w_out^T (fp32 store)
  gemm_out<<<dim3(8, 64), 256, 0, stream>>>(xb, woutb, out);
}

// Round 8
// 216.429 us; speedup vs baseline: 1.1545x; 1.1545x over previous
//
#include <hip/hip_runtime.h>
#include <hip/hip_bf16.h>
#include <stdint.h>

typedef __attribute__((ext_vector_type(8))) short bf16x8;
typedef __attribute__((ext_vector_type(4))) float f32x4;
typedef __attribute__((ext_vector_type(4))) unsigned short u16x4;

#define B_ 4
#define T_ 2048
#define C_ 1024
#define H_ 16
#define D_ 64

// round-to-nearest-even fp32 -> bf16
__device__ __forceinline__ unsigned short f2bf(float f) {
  union { float f; uint32_t u; } v; v.f = f;
  uint32_t u = v.u;
  uint32_t r = (u + 0x7FFFu + ((u >> 16) & 1u)) >> 16;
  return (unsigned short)r;
}

// fused cast of all three fp32 inputs -> bf16 (one launch instead of three)
__global__ void __launch_bounds__(256) cast_all(const float* __restrict__ x,
                                                const float* __restrict__ wqkv,
                                                const float* __restrict__ wout,
                                                unsigned short* __restrict__ xb,
                                                unsigned short* __restrict__ wqkvb,
                                                unsigned short* __restrict__ woutb) {
  int bid = blockIdx.x;
  const float* src; unsigned short* dst; int i;
  if (bid < 8192)       { src = x;    dst = xb;    i = bid * 256 + threadIdx.x; }
  else if (bid < 11264) { src = wqkv; dst = wqkvb; i = (bid - 8192) * 256 + threadIdx.x; }
  else                  { src = wout; dst = woutb; i = (bid - 11264) * 256 + threadIdx.x; }
  float4 f = ((const float4*)src)[i];
  u16x4 o;
  o[0] = f2bf(f.x); o[1] = f2bf(f.y); o[2] = f2bf(f.z); o[3] = f2bf(f.w);
  ((u16x4*)dst)[i] = o;
}

// ---------------------------------------------------------------------------
// QKV GEMM: C[8192,3072] = A[8192,1024] * W[3072,1024]^T, bf16, fp32 acc.
// 256x128 block tile, BK=32, 4 waves, per-wave 128x64 (acc[8][4]).
// 2-phase dbuf staging via global_load_lds width=16. SINGLE dispatch (the
// round-7 two-half split underfilled the 2-blocks/CU co-residency -> reverted).
// Epilogue: Q/K blocks -> LDS [128][132] transpose -> coalesced 16B scatter;
// V blocks -> packed u16x4 stores to vt[B,H,D,T] (transposed for attn's PV).
// ---------------------------------------------------------------------------
__global__ void __launch_bounds__(256, 2) gemm_qkv(const unsigned short* __restrict__ A,
                                                   const unsigned short* __restrict__ Bm,
                                                   unsigned short* __restrict__ qb,
                                                   unsigned short* __restrict__ kb,
                                                   unsigned short* __restrict__ vb) {
  __shared__ short lds[24576];  // 48KB: 2 bufs x (A 256x32 + B 128x32 shorts)
  const int tid = threadIdx.x;
  const int bm = blockIdx.y * 256;
  const int bn = blockIdx.x * 128;

  const int wave = tid >> 6;
  const int l = tid & 63;
  const int wm = wave >> 1, wn = wave & 1;   // wave-row (128 m), wave-col (64 n)
  const int lm = l & 15, lq = l >> 4;
  const int lr = l >> 2;           // row within 16-row staging chunk
  const int lc = (l & 3) << 3;     // k-col {0,8,16,24}

  f32x4 acc[8][4];
#pragma unroll
  for (int i = 0; i < 8; i++)
#pragma unroll
    for (int j = 0; j < 4; j++) acc[i][j] = (f32x4){0.f, 0.f, 0.f, 0.f};

  // staging: 24 chunks of 16 rows x 32 shorts (1KB); 0..15 -> A, 16..23 -> B.
  const unsigned short* gs[6];
  int ldo[6];
#pragma unroll
  for (int i = 0; i < 6; i++) {
    int c = wave * 6 + i;            // 0..23, wave-uniform
    if (c < 16) {
      gs[i] = A + (size_t)(bm + 16 * c + lr) * 1024 + lc;
      ldo[i] = c * 512;                      // A region [0,8192)
    } else {
      gs[i] = Bm + (size_t)(bn + 16 * (c - 16) + lr) * 1024 + lc;
      ldo[i] = 8192 + (c - 16) * 512;        // B region [8192,12288)
    }
  }

#define STAGE(curb, kk)                                                          \
  do {                                                                           \
    _Pragma("unroll")                                                            \
    for (int i = 0; i < 6; i++) {                                                \
      __builtin_amdgcn_global_load_lds(                                          \
          (__attribute__((address_space(1))) void*)(uintptr_t)(const void*)(gs[i] + (kk)), \
          (__attribute__((address_space(3))) void*)(lds + ldo[i] + (curb) * 12288),        \
          16, 0, 0);                                                             \
    }                                                                            \
  } while (0)

  STAGE(0, 0);
  int cur = 0;
  __syncthreads();  // prologue tile landed (vmcnt(0) drain) + visible to all

  for (int k0 = 0; k0 < 1024; k0 += 32) {
    if (k0 + 32 < 1024) STAGE(cur ^ 1, k0 + 32);  // issue next tile EARLY
    const short* As_ = lds + cur * 12288;
    const short* Bs_ = lds + cur * 12288 + 8192;
    bf16x8 Bf[4];
#pragma unroll
    for (int j = 0; j < 4; j++)
      Bf[j] = *(const bf16x8*)&Bs_[(wn * 64 + 16 * j + lm) * 32 + 8 * lq];
#pragma unroll
    for (int h = 0; h < 2; h++) {   // two m-halves reuse Bf
      bf16x8 Af[4];
#pragma unroll
      for (int i = 0; i < 4; i++)
        Af[i] = *(const bf16x8*)&As_[(wm * 128 + 64 * h + 16 * i + lm) * 32 + 8 * lq];
#pragma unroll
      for (int i = 0; i < 4; i++)
#pragma unroll
        for (int j = 0; j < 4; j++)
          acc[4 * h + i][j] =
              __builtin_amdgcn_mfma_f32_16x16x32_bf16(Af[i], Bf[j], acc[4 * h + i][j], 0, 0, 0);
    }
    __syncthreads();  // next tile's loads drained + everyone done reading cur
    cur ^= 1;
  }
#undef STAGE

  // C/D layout: col = lane&15, row = (lane>>4)*4 + reg  [measured m89/m91]
  if (bn >= 2048) {
    // V block: store TRANSPOSED vt[b,h,d,t]; acc[.][.][0..3] = 4 consecutive t.
#pragma unroll
    for (int h = 0; h < 2; h++)
#pragma unroll
      for (int i = 0; i < 4; i++)
#pragma unroll
        for (int j = 0; j < 4; j++) {
          int m0 = bm + wm * 128 + 64 * h + 16 * i + 4 * lq;   // t base (4-aligned)
          int n = (bn - 2048) + wn * 64 + 16 * j + lm;         // 0..1023
          int hh = n >> 6, d = n & 63;
          int b = m0 >> 11, t = m0 & 2047;
          u16x4 o;
#pragma unroll
          for (int r = 0; r < 4; r++) o[r] = f2bf(acc[4 * h + i][j][r]);
          *(u16x4*)&vb[(((size_t)(b * 16 + hh)) * 64 + d) * 2048 + t] = o;
        }
  } else {
    // Q/K block: LDS transpose [128][132] in two half-passes -> coalesced 16B stores
#pragma unroll
    for (int p = 0; p < 2; ++p) {
      if (p) __syncthreads();  // pass-0 reads done before overwrite
      if (wm == p) {
#pragma unroll
        for (int h = 0; h < 2; h++)
#pragma unroll
          for (int i = 0; i < 4; i++)
#pragma unroll
            for (int j = 0; j < 4; j++)
#pragma unroll
              for (int r = 0; r < 4; r++)
                lds[(64 * h + 16 * i + 4 * lq + r) * 132 + wn * 64 + 16 * j + lm] =
                    (short)f2bf(acc[4 * h + i][j][r]);
      }
      __syncthreads();
#pragma unroll
      for (int k = 0; k < 8; k++) {
        int c = tid + 256 * k;       // 2048 chunks of 8 shorts
        int row = c >> 4;            // 0..127
        int col = (c & 15) << 3;     // 0..120
        bf16x8 v = *(const bf16x8*)&lds[row * 132 + col];
        int m = bm + 128 * p + row, n = bn + col;
        int which = n >> 10, rem = n & 1023;
        int hh = rem >> 6, d = rem & 63;     // d 8-aligned, within one head
        int b = m >> 11, t = m & 2047;
        unsigned short* dst = (which == 0) ? qb : kb;
        *(bf16x8*)&dst[(((size_t)(b * 16 + hh)) * 2048 + t) * 64 + d] = v;
      }
    }
  }
}

// ---------------------------------------------------------------------------
// Out-proj GEMM: C[8192,1024] = A[8192,1024] * W[1024,1024]^T, fp32 out.
// 128x128 tile, BK=32, 2-phase dbuf (proven round-3 structure).
// ---------------------------------------------------------------------------
__global__ void __launch_bounds__(256) gemm_out(const unsigned short* __restrict__ A,
                                                const unsigned short* __restrict__ Bm,
                                                float* __restrict__ fo) {
  __shared__ short lds[16384];
  const int tid = threadIdx.x;
  const int bm = blockIdx.y * 128;
  const int bn = blockIdx.x * 128;
  const int wave = tid >> 6;
  const int l = tid & 63;
  const int wm = wave >> 1, wn = wave & 1;
  const int lm = l & 15, lq = l >> 4;
  const int lr = l >> 2;
  const int lc = (l & 3) << 3;

  f32x4 acc[4][4];
#pragma unroll
  for (int i = 0; i < 4; i++)
#pragma unroll
    for (int j = 0; j < 4; j++) acc[i][j] = (f32x4){0.f, 0.f, 0.f, 0.f};

  const unsigned short* gsrc[4];
  int ldoff[4];
#pragma unroll
  for (int i = 0; i < 4; i++) {
    int c = wave * 4 + i;
    if (c < 8) {
      gsrc[i] = A + (size_t)(bm + 16 * c + lr) * 1024 + lc;
      ldoff[i] = (16 * c) * 32;
    } else {
      gsrc[i] = Bm + (size_t)(bn + 16 * (c - 8) + lr) * 1024 + lc;
      ldoff[i] = 8192 + (16 * (c - 8)) * 32;
    }
  }

#define STAGE(curb, kk)                                                          \
  do {                                                                           \
    _Pragma("unroll")                                                            \
    for (int i = 0; i < 4; i++) {                                                \
      __builtin_amdgcn_global_load_lds(                                          \
          (__attribute__((address_space(1))) void*)(uintptr_t)(const void*)(gsrc[i] + (kk)), \
          (__attribute__((address_space(3))) void*)(lds + ldoff[i] + (curb) * 4096),         \
          16, 0, 0);                                                             \
    }                                                                            \
  } while (0)

  STAGE(0, 0);
  int cur = 0;
  __syncthreads();

  for (int k0 = 0; k0 < 1024; k0 += 32) {
    if (k0 + 32 < 1024) STAGE(cur ^ 1, k0 + 32);
    bf16x8 af[4], bfr[4];
#pragma unroll
    for (int i = 0; i < 4; i++)
      af[i] = *(const bf16x8*)&lds[cur * 4096 + (wm * 64 + 16 * i + lm) * 32 + 8 * lq];
#pragma unroll
    for (int j = 0; j < 4; j++)
      bfr[j] = *(const bf16x8*)&lds[8192 + cur * 4096 + (wn * 64 + 16 * j + lm) * 32 + 8 * lq];
#pragma unroll
    for (int i = 0; i < 4; i++)
#pragma unroll
      for (int j = 0; j < 4; j++)
        acc[i][j] = __builtin_amdgcn_mfma_f32_16x16x32_bf16(af[i], bfr[j], acc[i][j], 0, 0, 0);
    __syncthreads();
    cur ^= 1;
  }
#undef STAGE

#pragma unroll
  for (int i = 0; i < 4; i++)
#pragma unroll
    for (int j = 0; j < 4; j++)
#pragma unroll
      for (int r = 0; r < 4; r++) {
        int m = bm + wm * 64 + 16 * i + 4 * lq + r;
        int n = bn + wn * 64 + 16 * j + lm;
        fo[(size_t)m * 1024 + n] = acc[i][j][r];
      }
}

// ---------------------------------------------------------------------------
// Sliding-window causal flash attention, SWAPPED-QK^T lane-local softmax.
// One wave owns 32 q-rows (2 subtiles of 16); K/V chunk = 32 keys.
// QK^T computed as mfma(A=K_frag, B=Q_frag) -> S^T: each lane (lq,lm) holds
// S[k=j0+16hh+4lq+r][q=t0q+lm] -- the SOFTMAX AXIS (k) is lane-local+lq-group:
// row-max/sum = in-register chain + 2 shfl_xor (16,32), replacing the old
// 16-wide butterflies (32 shuffles -> 8 incl. broadcasts). The same register
// data serves K as A-frag and Q as B-frag (row-major X == A-frag of X, B-frag
// of X^T) so loads are unchanged. P lands in P[q][k] row layout -> same LDS
// write/read -> K=32 PV mfma as before. Masked-score poison guarded (p=0).
// q/k in [B,H,T,D] bf16; v transposed vt[B,H,D,T]; out [B,T,H*D] bf16.
// __launch_bounds__(256,4): cap VGPR at 128 -> 4 blocks/CU (grid 1024) = 16 waves/CU.
// ---------------------------------------------------------------------------
__global__ void __launch_bounds__(256, 4) attn_swa(const unsigned short* __restrict__ Qb,
                                                   const unsigned short* __restrict__ Kb,
                                                   const unsigned short* __restrict__ Vt,
                                                   unsigned short* __restrict__ Ob) {
  __shared__ short P[4][16 * 48];  // per-wave P[q=16][k=32], row stride 48 (16B-aligned rows)
  const int wv = threadIdx.x >> 6;
  const int l = threadIdx.x & 63;
  const int wid = blockIdx.x * 4 + wv;   // 0..4095
  const int bh = wid >> 6;               // 64 32-row q-groups per (b,h)
  const int t0 = (wid & 63) << 5;
  const int lm = l & 15, lq = l >> 4;
  const size_t base = (size_t)bh * (T_ * D_);

  // Q fragments (swapped-QK B-operand): lane holds Q[t0q+lm][8lq+j], two d-halves
  bf16x8 qf[2][2];
#pragma unroll
  for (int qt = 0; qt < 2; qt++) {
    qf[qt][0] = *(const bf16x8*)(Qb + base + (size_t)(t0 + 16 * qt + lm) * 64 + 8 * lq);
    qf[qt][1] = *(const bf16x8*)(Qb + base + (size_t)(t0 + 16 * qt + lm) * 64 + 32 + 8 * lq);
  }

  float mst[2] = {-1e30f, -1e30f}, lst[2] = {0.f, 0.f};
  f32x4 Oa[2][4];  // Oa[qt][jt][r] = O[t0q+4lq+r][16jt+lm]
#pragma unroll
  for (int qt = 0; qt < 2; qt++)
#pragma unroll
    for (int jt = 0; jt < 4; jt++) Oa[qt][jt] = (f32x4){0.f, 0.f, 0.f, 0.f};

  const float cs = 0.125f * 1.44269504f;  // scale * log2(e)
  int jstart = t0 - 128; if (jstart < 0) jstart = 0;

  for (int j0 = jstart; j0 < t0 + 32; j0 += 32) {
    // K fragments (A-operand): lane holds K[j0+16hh+lm][8lq+j]; rows <= t0+31 <= 2047
    bf16x8 ka[2][2];
#pragma unroll
    for (int hh = 0; hh < 2; hh++) {
      int kr = j0 + 16 * hh + lm;
      ka[hh][0] = *(const bf16x8*)(Kb + base + (size_t)kr * 64 + 8 * lq);
      ka[hh][1] = *(const bf16x8*)(Kb + base + (size_t)kr * 64 + 32 + 8 * lq);
    }
    // V fragments (PV B-operand, K=32): vf[jt] = V[k=j0+8lq+j][d=16jt+lm], contiguous in vt
    bf16x8 vf[4];
#pragma unroll
    for (int jt = 0; jt < 4; jt++)
      vf[jt] = *(const bf16x8*)(Vt + base + (size_t)(16 * jt + lm) * 2048 + j0 + 8 * lq);

#pragma unroll
    for (int qt = 0; qt < 2; qt++) {
      const int t0q = t0 + 16 * qt;
      const int t = t0q + lm;           // q-row owned by this lane for softmax
      // S^T[k][q]: two d-half mfma pairs
      f32x4 s0 = (f32x4){0.f, 0.f, 0.f, 0.f}, s1 = (f32x4){0.f, 0.f, 0.f, 0.f};
      s0 = __builtin_amdgcn_mfma_f32_16x16x32_bf16(ka[0][0], qf[qt][0], s0, 0, 0, 0);
      s0 = __builtin_amdgcn_mfma_f32_16x16x32_bf16(ka[0][1], qf[qt][1], s0, 0, 0, 0);
      s1 = __builtin_amdgcn_mfma_f32_16x16x32_bf16(ka[1][0], qf[qt][0], s1, 0, 0, 0);
      s1 = __builtin_amdgcn_mfma_f32_16x16x32_bf16(ka[1][1], qf[qt][1], s1, 0, 0, 0);
      // mask + max (lane-local chain over 8, then 2 shuffles across lq groups)
      float sv[8];
      float m2 = -1e30f;
#pragma unroll
      for (int hh = 0; hh < 2; hh++)
#pragma unroll
        for (int r = 0; r < 4; r++) {
          int k = j0 + 16 * hh + 4 * lq + r;
          float x = (hh ? s1[r] : s0[r]) * cs;
          bool okm = (k <= t) && (k + 128 >= t);
          sv[hh * 4 + r] = okm ? x : -1e30f;
          m2 = fmaxf(m2, sv[hh * 4 + r]);
        }
      m2 = fmaxf(m2, __shfl_xor(m2, 16));
      m2 = fmaxf(m2, __shfl_xor(m2, 32));
      float mn = fmaxf(mst[qt], m2);
      float a = __builtin_amdgcn_exp2f(mst[qt] - mn);
      float ps = 0.f;
#pragma unroll
      for (int i = 0; i < 8; i++) {
        sv[i] = (sv[i] > -1e29f) ? __builtin_amdgcn_exp2f(sv[i] - mn) : 0.f;  // poison guard
        ps += sv[i];
      }
      ps += __shfl_xor(ps, 16);
      ps += __shfl_xor(ps, 32);
      lst[qt] = lst[qt] * a + ps;
      mst[qt] = mn;
      // P -> LDS: P[q=lm][k=16hh+4lq+r] (8B aligned: 96*lm + 32*hh + 8*lq bytes)
#pragma unroll
      for (int hh = 0; hh < 2; hh++) {
        u16x4 pk;
#pragma unroll
        for (int r = 0; r < 4; r++) pk[r] = f2bf(sv[hh * 4 + r]);
        *(u16x4*)&P[wv][lm * 48 + 16 * hh + 4 * lq] = pk;
      }
      // rescale O: a (uniform across lq, indexed by lm=q) -> broadcast to q=4lq+r
      float al[4];
#pragma unroll
      for (int r = 0; r < 4; r++) al[r] = __shfl(a, 4 * lq + r);
#pragma unroll
      for (int jt = 0; jt < 4; jt++)
#pragma unroll
        for (int r = 0; r < 4; r++) Oa[qt][jt][r] *= al[r];
      // PV: A-frag P[q=lm][8lq+j] (same-wave LDS, in-order, no barrier), B = vf
      bf16x8 pa = *(const bf16x8*)&P[wv][lm * 48 + 8 * lq];
#pragma unroll
      for (int jt = 0; jt < 4; jt++)
        Oa[qt][jt] = __builtin_amdgcn_mfma_f32_16x16x32_bf16(pa, vf[jt], Oa[qt][jt], 0, 0, 0);
    }
  }
  const int b = bh >> 4, h = bh & 15;
#pragma unroll
  for (int qt = 0; qt < 2; qt++) {
    float inv = 1.0f / lst[qt];       // valid in lane's q=t0q+lm
    float invl[4];
#pragma unroll
    for (int r = 0; r < 4; r++) invl[r] = __shfl(inv, 4 * lq + r);
#pragma unroll
    for (int r = 0; r < 4; r++) {
      int t = t0 + 16 * qt + 4 * lq + r;
#pragma unroll
      for (int jt = 0; jt < 4; jt++) {
        int c = h * 64 + 16 * jt + lm;
        Ob[((size_t)(b * T_ + t)) * 1024 + c] = f2bf(Oa[qt][jt][r] * invl[r]);
      }
    }
  }
}

extern "C" void kernel_launch(void* const* d_in, const int* in_sizes, int n_in,
                              void* d_out, int out_size, void* d_ws, size_t ws_size,
                              hipStream_t stream) {
  const float* x = (const float*)d_in[0];       // [4,2048,1024]
  const float* w_qkv = (const float*)d_in[1];   // [3072,1024]
  const float* w_out = (const float*)d_in[2];   // [1024,1024]
  float* out = (float*)d_out;                   // [4,2048,1024] fp32

  // workspace layout (bf16 = unsigned short), ~72 MB total
  unsigned short* xb = (unsigned short*)d_ws;                // 8192*1024 (reused as attn out)
  unsigned short* wqkvb = xb + (size_t)8192 * 1024;          // 3072*1024
  unsigned short* woutb = wqkvb + (size_t)3072 * 1024;       // 1024*1024
  unsigned short* qb = woutb + (size_t)1024 * 1024;          // 64*2048*64
  unsigned short* kb = qb + (size_t)64 * 2048 * 64;
  unsigned short* vb = kb + (size_t)64 * 2048 * 64;          // holds vt[B,H,D,T]

  cast_all<<<12288, 256, 0, stream>>>(x, w_qkv, w_out, xb, wqkvb, woutb);

  // qkv = x @ w_qkv^T -> q/k [B,H,T,D] + v transposed [B,H,D,T] (single dispatch)
  gemm_qkv<<<dim3(24, 32), 256, 0, stream>>>(xb, wqkvb, qb, kb, vb);

  // sliding-window attention -> [B,T,C] bf16 (aliases xb; dead after gemm_qkv)
  attn_swa<<<1024, 256, 0, stream>>>(qb, kb, vb, xb);

  // out = attn @ w_out^T (fp32 store)
  gemm_out<<<dim3(8, 64), 256, 0, stream>>>(xb, woutb, out);
}